// Round 15
// baseline (2284.830 us; speedup 1.0000x reference)
//
#include <hip/hip_runtime.h>
#include <hip/hip_bf16.h>
#include <stdint.h>

// SelfAttention B=4 S=4096 D=1024, fp32 in/out. Single-bf16 pipeline:
//   cvt -> {Q,K} proj (z=2, NW8), Vt = Wv@X^T (NW4) -> scores
//   P~=exp(QK^T/32) bf16 + row partial sums (z=4, NW8) -> PV out=(P~V)/rowsum
//   (z=4, NW4). No softmax kernel.
// R15 vs R13: BK 64->32 to double occupancy. NW8 (512thr, 256x256 tile):
// LDS 64KB -> 2 blocks/CU (4 waves/SIMD). NW4 (256thr, 128x256 tile):
// LDS 48KB -> 3 blocks/CU; used for V^T proj and PV whose grids were only
// 256 blocks (now 512). Per-wave geometry unchanged: 128x64 out, acc[8][4],
// 2 lockstep phases of 16 MFMA per K-tile (r13 schedule, best measured),
// 3 barriers/K-tile, counted vmcnt(4) (tile t+1 waited one full iter after
// issue). Swizzle for 32-elem rows: slot ^= (row>>1)&3 -> 2-way bank
// aliasing (free, m136); gload_lds dest linear + inverse-swizzled source.

typedef __attribute__((ext_vector_type(4))) float f32x4;
typedef __attribute__((ext_vector_type(8))) short s16x8;
typedef __attribute__((ext_vector_type(4))) unsigned short u16x4;
typedef unsigned int u32;
typedef unsigned short u16;

__device__ __forceinline__ u16 f2b(float f) {   // fp32 -> bf16 RNE
  u32 u = __float_as_uint(f);
  u = (u + 0x7FFFu + ((u >> 16) & 1u)) >> 16;
  return (u16)u;
}
__device__ __forceinline__ float b2f(u16 h) {
  return __uint_as_float(((u32)h) << 16);
}

__device__ __forceinline__ void gload_lds16(const void* g, void* l) {
  __builtin_amdgcn_global_load_lds(
      (const __attribute__((address_space(1))) void*)(const void*)g,
      (__attribute__((address_space(3))) void*)(void*)l, 16, 0, 0);
}

#define BARRIER() asm volatile("s_barrier" ::: "memory")
#define WAITLGKM0() asm volatile("s_waitcnt lgkmcnt(0)" ::: "memory")
#define WAITVM(N) asm volatile("s_waitcnt vmcnt(" #N ")" ::: "memory")

// ---------------- fp32 -> bf16 convert ----------------
__global__ __launch_bounds__(256) void k_cvt(const float* __restrict__ in,
                                             u16* __restrict__ out, int n4) {
  int i = blockIdx.x * 256 + threadIdx.x;
  if (i >= n4) return;
  f32x4 f = ((const f32x4*)in)[i];
  u16x4 h;
#pragma unroll
  for (int j = 0; j < 4; ++j) h[j] = f2b(f[j]);
  ((u16x4*)out)[i] = h;
}

// ---- BMx256 NT GEMM, BK=32, 16x16x32 bf16 MFMA, NW waves (BM=NW*32) ----
// C[M,N] = sum_k A[m,k]*B[n,k]. Per-wave output 128x64, acc[8][4].
// MODE 0 (NW8): bias[col] + bf16 store (Q/K proj; z=1 uses biasB)
// MODE 1 (NW4): bias[row] + bf16 store (V^T proj)
// MODE 2 (NW8): bf16 store of exp(v*scale); per-row partial sums -> part
// MODE 3 (NW4): fp32 store of v / rowsum (PV out)
template <int MODE, int NW>
__global__ __launch_bounds__(NW * 64, NW == 8 ? 4 : 3)
void k_gemm32(const u16* __restrict__ A, const u16* __restrict__ B, int lda,
              int ldb, int K, const float* __restrict__ bias,
              const float* __restrict__ biasB, void* __restrict__ Cv, int ldc,
              float scale, size_t az, size_t bz, size_t czb,
              float* __restrict__ part) {
  constexpr int THREADS = NW * 64;
  constexpr int BM = NW * 32;              // 256 (NW8) / 128 (NW4)
  constexpr int PERBUF = (BM + 256) * 32;  // u16 per double-buffer half
  extern __shared__ __align__(16) u16 lds[];

  A += (size_t)blockIdx.z * az;
  B += (size_t)blockIdx.z * bz;
  char* C = (char*)Cv + (size_t)blockIdx.z * czb;
  const float* bi = (MODE == 0 && blockIdx.z != 0) ? biasB : bias;

  // bijective XCD-aware swizzle
  const int gx = gridDim.x;
  const int nwg = gx * gridDim.y;
  const int bid = blockIdx.y * gx + blockIdx.x;
  const int q = nwg >> 3, r = nwg & 7;
  const int xcd = bid & 7, idx = bid >> 3;
  const int tile = (xcd < r ? xcd * (q + 1) : r * (q + 1) + (xcd - r) * q) + idx;
  const int m0 = (tile / gx) * BM;
  const int n0 = (tile % gx) * 256;

  const int tid = threadIdx.x;
  const int lane = tid & 63;
  const int wid = tid >> 6;
  const int wm = (NW == 8) ? (wid >> 2) : 0;  // M half (NW8) / 0 (NW4)
  const int wn = wid & 3;                     // N quarter

  // staging: thread covers 16B = 1/4 row; row = base + (tid>>2)
  const int gcol = (((tid & 3) ^ ((tid >> 3) & 3)) << 3);  // inv-swizzled col
  // ds_read: lane reads row (.. + rA) at k-slot kq; phys slot ^= (row>>1)&3
  const int rA = lane & 15;
  const int kq = (lane >> 4) << 3;                    // 0,8,16,24
  const int xr2 = ((((lane & 15) >> 1) & 3) << 3);    // f(row)<<3, lane-const

#define STAGE(kt, b)                                                         \
  do {                                                                       \
    _Pragma("unroll") for (int j = 0; j < BM * 4 / THREADS; ++j)             \
        gload_lds16(A + (size_t)(m0 + j * (THREADS / 4) + (tid >> 2)) * lda  \
                        + (kt) * 32 + gcol,                                  \
                    &lds[(b)*PERBUF + j * THREADS * 8 + tid * 8]);           \
    _Pragma("unroll") for (int j = 0; j < 1024 / THREADS; ++j)               \
        gload_lds16(B + (size_t)(n0 + j * (THREADS / 4) + (tid >> 2)) * ldb  \
                        + (kt) * 32 + gcol,                                  \
                    &lds[(b)*PERBUF + BM * 32 + j * THREADS * 8 + tid * 8]); \
  } while (0)
#define RD_A(dst, b, sub)                                                    \
  do {                                                                       \
    _Pragma("unroll") for (int mi = 0; mi < 4; ++mi)                         \
        dst[mi] = *(const s16x8*)&lds[(b)*PERBUF +                           \
            (wm * 128 + (sub) + mi * 16 + rA) * 32 + (kq ^ xr2)];            \
  } while (0)
#define RD_B(dst, b)                                                         \
  do {                                                                       \
    _Pragma("unroll") for (int nj = 0; nj < 4; ++nj)                         \
        dst[nj] = *(const s16x8*)&lds[(b)*PERBUF + BM * 32 +                 \
            (wn * 64 + nj * 16 + rA) * 32 + (kq ^ xr2)];                     \
  } while (0)
#define MM(AF, BF, MO)                                                       \
  do {                                                                       \
    _Pragma("unroll") for (int mi = 0; mi < 4; ++mi)                         \
        _Pragma("unroll") for (int nj = 0; nj < 4; ++nj)                     \
            acc[(MO) + mi][nj] = __builtin_amdgcn_mfma_f32_16x16x32_bf16(    \
                AF[mi], BF[nj], acc[(MO) + mi][nj], 0, 0, 0);                \
  } while (0)

  f32x4 acc[8][4] = {};
  const int NT = K >> 5;

  // prologue: K0->buf0, K1->buf1 (4 gloads each); retire K0's 4
  STAGE(0, 0);
  if (NT > 1) {
    STAGE(1, 1);
    WAITVM(4);
  } else {
    WAITVM(0);
  }
  BARRIER();

  s16x8 af0[4], af1[4], bf[4];
  for (int t = 0; t < NT; ++t) {
    const int b = t & 1;
    // ph1: rows 0-63 of wave half x all 4 n-frags
    RD_A(af0, b, 0);
    RD_B(bf, b);
    WAITLGKM0();
    __builtin_amdgcn_s_setprio(1);
    MM(af0, bf, 0);
    __builtin_amdgcn_s_setprio(0);
    BARRIER();  // #1
    // ph2: rows 64-127
    RD_A(af1, b, 64);
    WAITLGKM0();
    __builtin_amdgcn_s_setprio(1);
    MM(af1, bf, 4);
    __builtin_amdgcn_s_setprio(0);
    BARRIER();  // #2: all reads of buf b complete block-wide
    if (t + 2 < NT) {
      STAGE(t + 2, b);  // restage into just-read buffer
      WAITVM(4);        // retire K(t+1)'s 4 (issued one full iter ago)
      BARRIER();        // #3: next iter may read buf b^1
    } else if (t + 1 < NT) {
      WAITVM(0);
      BARRIER();
    }
  }

  // ---- coalesced epilogue via LDS: BM/32 chunks of 32 rows x 256 cols ----
  // fl = [32][260] f32 (33280 B); rinv just past it.
  float* fl = (float*)lds;
  float* rinv = fl + 8320;
  const int l15 = lane & 15;
  const int r4 = (lane >> 4) * 4;
  f32x4 bcol4 = {0.f, 0.f, 0.f, 0.f};
  if (MODE == 0) bcol4 = *(const f32x4*)&bi[n0 + lane * 4];
  if (MODE == 3) {
    if (tid < BM) {
      const float* pr = &part[((size_t)blockIdx.z * 4096 + m0 + tid) * 16];
      float s = 0.f;
#pragma unroll
      for (int j = 0; j < 4; ++j) {
        f32x4 t4 = *(const f32x4*)&pr[j * 4];
        s += (t4[0] + t4[1]) + (t4[2] + t4[3]);
      }
      rinv[tid] = 1.0f / s;
    }
  }
#pragma unroll
  for (int c = 0; c < BM / 32; ++c) {
    __syncthreads();  // K-loop done / prior chunk's reads done (incl rinv w)
    if (wm == (c >> 2)) {
      const int mibase = (c & 3) * 2;
#pragma unroll
      for (int mi2 = 0; mi2 < 2; ++mi2) {
#pragma unroll
        for (int nj = 0; nj < 4; ++nj) {
          const int col = wn * 64 + nj * 16 + l15;
          const int rbase = mi2 * 16 + r4;
#pragma unroll
          for (int rr = 0; rr < 4; ++rr) {
            float v = acc[mibase + mi2][nj][rr];
            if (MODE == 2) v = __expf(v * scale);  // exp fused here
            fl[(rbase + rr) * 260 + col] = v;
          }
        }
      }
    }
    __syncthreads();
#pragma unroll
    for (int p = 0; p < 2048 / THREADS; ++p) {
      const int rl = p * NW + wid;  // 32 rows per chunk
      const int rowg = m0 + c * 32 + rl;
      f32x4 v = *(const f32x4*)&fl[rl * 260 + lane * 4];
      if (MODE == 0) {
#pragma unroll
        for (int j = 0; j < 4; ++j) v[j] += bcol4[j];
        u16x4 h;
#pragma unroll
        for (int j = 0; j < 4; ++j) h[j] = f2b(v[j]);
        ((u16x4*)((u16*)C + (size_t)rowg * ldc + n0))[lane] = h;
      } else if (MODE == 1) {
        const float br = bi[rowg];
        u16x4 h;
#pragma unroll
        for (int j = 0; j < 4; ++j) h[j] = f2b(v[j] + br);
        ((u16x4*)((u16*)C + (size_t)rowg * ldc + n0))[lane] = h;
      } else if (MODE == 2) {
        u16x4 h;  // already exp'd
#pragma unroll
        for (int j = 0; j < 4; ++j) h[j] = f2b(v[j]);
        ((u16x4*)((u16*)C + (size_t)rowg * ldc + n0))[lane] = h;
      } else {
        const float iv = rinv[c * 32 + rl];
#pragma unroll
        for (int j = 0; j < 4; ++j) v[j] *= iv;
        ((f32x4*)((float*)C + (size_t)rowg * ldc + n0))[lane] = v;
      }
    }
    if (MODE == 2) {
      // row partial sums: 16 threads/row, each sums 16 floats, 4 shuffles
      const int row16 = tid >> 4;  // 0..31
      const int seg = tid & 15;
      const float* rp = &fl[row16 * 260 + seg * 16];
      f32x4 s4 = {0.f, 0.f, 0.f, 0.f};
#pragma unroll
      for (int j = 0; j < 4; ++j) {
        f32x4 t4 = *(const f32x4*)&rp[j * 4];
#pragma unroll
        for (int d = 0; d < 4; ++d) s4[d] += t4[d];
      }
      float s = (s4[0] + s4[1]) + (s4[2] + s4[3]);
      s += __shfl_xor(s, 1, 64);
      s += __shfl_xor(s, 2, 64);
      s += __shfl_xor(s, 4, 64);
      s += __shfl_xor(s, 8, 64);
      if (seg == 0)
        part[((size_t)blockIdx.z * 4096 + m0 + c * 32 + row16) * 16 +
             (n0 >> 8)] = s;
    }
  }
#undef STAGE
#undef RD_A
#undef RD_B
#undef MM
}

extern "C" void kernel_launch(void* const* d_in, const int* in_sizes, int n_in,
                              void* d_out, int out_size, void* d_ws,
                              size_t ws_size, hipStream_t stream) {
  const float* x = (const float*)d_in[0];
  const float* Wq = (const float*)d_in[1];
  const float* bq = (const float*)d_in[2];
  const float* Wk = (const float*)d_in[3];
  const float* bk = (const float*)d_in[4];
  const float* Wv = (const float*)d_in[5];
  const float* bv = (const float*)d_in[6];
  float* out = (float*)d_out;
  char* ws = (char*)d_ws;

  const size_t MB = 1ull << 20;
  u16* Qb = (u16*)(ws + 0 * MB);      // [4][4096][1024] bf16
  u16* Kb = (u16*)(ws + 32 * MB);     // [4][4096][1024] bf16 (adjacent)
  u16* VtAll = (u16*)(ws + 64 * MB);  // [1024][16384] bf16 (V^T all batches)
  u16* Xb = (u16*)(ws + 96 * MB);     // [16384][1024] bf16, dead after proj
  u16* Sc = (u16*)(ws + 96 * MB);     // [4][4096][4096] bf16 P~, reuses Xb
  u16* Wqb = (u16*)(ws + 224 * MB);
  u16* Wkb = Wqb + 1048576;           // z-stride 1048576 elements
  u16* Wvb = Wqb + 2097152;
  float* part = (float*)(ws + 231 * MB);  // [4][4096][16] f32 partial sums

  hipFuncSetAttribute((const void*)k_gemm32<0, 8>,
                      hipFuncAttributeMaxDynamicSharedMemorySize, 65536);
  hipFuncSetAttribute((const void*)k_gemm32<2, 8>,
                      hipFuncAttributeMaxDynamicSharedMemorySize, 65536);
  hipFuncSetAttribute((const void*)k_gemm32<1, 4>,
                      hipFuncAttributeMaxDynamicSharedMemorySize, 49152);
  hipFuncSetAttribute((const void*)k_gemm32<3, 4>,
                      hipFuncAttributeMaxDynamicSharedMemorySize, 49152);

  // converts (x: 16,777,216 floats = 4,194,304 float4)
  k_cvt<<<16384, 256, 0, stream>>>(x, Xb, 4194304);
  k_cvt<<<1024, 256, 0, stream>>>(Wq, Wqb, 262144);
  k_cvt<<<1024, 256, 0, stream>>>(Wk, Wkb, 262144);
  k_cvt<<<1024, 256, 0, stream>>>(Wv, Wvb, 262144);

  // Q+K projections (NW8, 512 blocks): z=0 -> Q (bq), z=1 -> K (bk)
  k_gemm32<0, 8><<<dim3(4, 64, 2), dim3(512), 65536, stream>>>(
      Xb, Wqb, 1024, 1024, 1024, bq, bk, Qb, 1024, 1.f, 0, 1048576,
      (size_t)32 * MB, nullptr);
  // V^T projection (NW4, 512 blocks): C[d][s] = Wv@X^T + bv[d]; M=1024
  k_gemm32<1, 4><<<dim3(64, 8, 1), dim3(256), 49152, stream>>>(
      Wvb, Xb, 1024, 1024, 1024, bv, nullptr, VtAll, 16384, 1.f, 0, 0, 0,
      nullptr);
  // scores (NW8, 1024 blocks): P~ = exp(QK^T/32) bf16 + row partial sums
  k_gemm32<2, 8><<<dim3(16, 16, 4), dim3(512), 65536, stream>>>(
      Qb, Kb, 1024, 1024, 1024, nullptr, nullptr, Sc, 4096, 0.03125f, 4194304,
      4194304, (size_t)4096 * 4096 * 2, part);
  // PV (NW4, 512 blocks): out = (P~ V) / rowsum; M=4096, N=1024, K=4096
  k_gemm32<3, 4><<<dim3(4, 32, 4), dim3(256), 49152, stream>>>(
      Sc, VtAll, 4096, 16384, 4096, nullptr, nullptr, out, 1024, 1.f, 16777216,
      4096, (size_t)4096 * 1024 * 4, part);
}

// Round 16
// 414.885 us; speedup vs baseline: 5.5071x; 5.5071x over previous
//
#include <hip/hip_runtime.h>
#include <hip/hip_bf16.h>
#include <stdint.h>

// SelfAttention B=4 S=4096 D=1024, fp32 in/out. Single-bf16 pipeline:
//   cvt -> {Q,K} proj (one z=2 launch), Vt = Wv@X^T (transposed direct)
//   -> scores kernel: P~ = exp(QK^T/32) bf16 + per-row partial sums (z=4)
//   -> PV kernel: out = (P~ V) / rowsum (z=4). No softmax kernel.
// R16 = R13 ledger + m201 phase ORDERING (the one untried delta vs the
// verified 62%-MfmaUtil template): each phase is {issue ds_reads (+stage)
// -> s_barrier -> lgkmcnt(0) -> MFMA -> s_barrier}. Read latency hides
// under the barrier wait instead of being serially drained before it.
// 2 K-tiles unrolled per loop iter (static LDS buffer indices).
// WAR ledger (same as R13): A-reads issued ph1/ph2, drained by each wave's
// post-barrier lgkm0 inside ph2 -> ph2-end barrier certifies A free ->
// stage A(t+2) at ph3. B-reads end ph3 -> stage B(t+2) at ph4. vmcnt(8) at
// ph4 (pre-barrier) retires tile t+1's 8 loads (issued a full iter ago)
// before the barrier that gates next-tile reads.
// R15 lesson: this geometry needs ~256 combined VGPR+AGPR (acc alone = 128
// f32/lane); never force min-waves via __launch_bounds__ -> scratch spill.
// GEMM: 256x256 tile, BK=64, 8 waves (2Mx4N), 16x16x32 MFMA, T2 st-XOR
// swizzle, T1 bijective XCD swizzle, coalesced LDS-staged epilogue with
// fused exp/rowsum (MODE 2) and rowsum^-1 normalization (MODE 3).

typedef __attribute__((ext_vector_type(4))) float f32x4;
typedef __attribute__((ext_vector_type(8))) short s16x8;
typedef __attribute__((ext_vector_type(4))) unsigned short u16x4;
typedef unsigned int u32;
typedef unsigned short u16;

__device__ __forceinline__ u16 f2b(float f) {   // fp32 -> bf16 RNE
  u32 u = __float_as_uint(f);
  u = (u + 0x7FFFu + ((u >> 16) & 1u)) >> 16;
  return (u16)u;
}
__device__ __forceinline__ float b2f(u16 h) {
  return __uint_as_float(((u32)h) << 16);
}

__device__ __forceinline__ void gload_lds16(const void* g, void* l) {
  __builtin_amdgcn_global_load_lds(
      (const __attribute__((address_space(1))) void*)(const void*)g,
      (__attribute__((address_space(3))) void*)(void*)l, 16, 0, 0);
}

#define BARRIER() asm volatile("s_barrier" ::: "memory")
#define WAITLGKM0() asm volatile("s_waitcnt lgkmcnt(0)" ::: "memory")
#define WAITVM(N) asm volatile("s_waitcnt vmcnt(" #N ")" ::: "memory")

// ---------------- fp32 -> bf16 convert ----------------
__global__ __launch_bounds__(256) void k_cvt(const float* __restrict__ in,
                                             u16* __restrict__ out, int n4) {
  int i = blockIdx.x * 256 + threadIdx.x;
  if (i >= n4) return;
  f32x4 f = ((const f32x4*)in)[i];
  u16x4 h;
#pragma unroll
  for (int j = 0; j < 4; ++j) h[j] = f2b(f[j]);
  ((u16x4*)out)[i] = h;
}

// ------------- 256^2 8-phase NT GEMM, 16x16x32 bf16 MFMA -------------
// C[M,N] = sum_k A[m,k]*B[n,k].
// MODE 0: bias[col] + bf16 store (Q/K proj; z=1 uses biasB)
// MODE 1: bias[row] + bf16 store (V^T proj)
// MODE 2: bf16 store of exp(v*scale); per-row partial sums -> part
// MODE 3: fp32 store of v / rowsum (rowsum = sum of 16 partials) (PV out)
template <int MODE>
__global__ __launch_bounds__(512)
void k_gemm256(const u16* __restrict__ A, const u16* __restrict__ B, int lda,
               int ldb, int K, const float* __restrict__ bias,
               const float* __restrict__ biasB, void* __restrict__ Cv, int ldc,
               float scale, size_t az, size_t bz, size_t czb,
               float* __restrict__ part) {
  extern __shared__ __align__(16) u16 lds[];  // 131072 B

  A += (size_t)blockIdx.z * az;
  B += (size_t)blockIdx.z * bz;
  char* C = (char*)Cv + (size_t)blockIdx.z * czb;
  const float* bi = (MODE == 0 && blockIdx.z != 0) ? biasB : bias;

  // bijective XCD-aware swizzle
  const int gx = gridDim.x;
  const int nwg = gx * gridDim.y;
  const int bid = blockIdx.y * gx + blockIdx.x;
  const int q = nwg >> 3, r = nwg & 7;
  const int xcd = bid & 7, idx = bid >> 3;
  const int tile = (xcd < r ? xcd * (q + 1) : r * (q + 1) + (xcd - r) * q) + idx;
  const int m0 = (tile / gx) * 256;
  const int n0 = (tile % gx) * 256;

  const int tid = threadIdx.x;
  const int lane = tid & 63;
  const int wid = tid >> 6;
  const int wm = wid >> 2;  // 0..1 (M half)
  const int wn = wid & 3;   // 0..3 (N quarter)

  // staging: one STAGE = one 128x64 half-tile = 2 gload_lds per thread
  const int srow = lane >> 3;                       // 0..7
  const int gcol = (((lane & 7) ^ srow) << 3);      // inverse-swizzled col
  // ds_read constants (16x16 layout, conflict-free measured r5)
  const int rA = lane & 15;
  const int kq = (lane >> 4) << 3;                  // 0,8,16,24
  const int xr = (lane & 7) << 3;                   // read-side swizzle

#define STAGE_A(h, kt, b)                                                    \
  do {                                                                       \
    _Pragma("unroll") for (int j = 0; j < 2; ++j)                            \
        gload_lds16(A + (size_t)(m0 + (h)*128 + j * 64 + wid * 8 + srow) *   \
                            lda + (kt)*64 + gcol,                            \
                    &lds[(b)*32768 + (h)*8192 + j * 4096 + wid * 512]);      \
  } while (0)
#define STAGE_B(h, kt, b)                                                    \
  do {                                                                       \
    _Pragma("unroll") for (int j = 0; j < 2; ++j)                            \
        gload_lds16(B + (size_t)(n0 + (h)*128 + j * 64 + wid * 8 + srow) *   \
                            ldb + (kt)*64 + gcol,                            \
                    &lds[(b)*32768 + 16384 + (h)*8192 + j * 4096 +           \
                         wid * 512]);                                        \
  } while (0)
#define RD_A(dst, b, sub)                                                    \
  do {                                                                       \
    _Pragma("unroll") for (int mi = 0; mi < 4; ++mi)                         \
        _Pragma("unroll") for (int ks = 0; ks < 2; ++ks)                     \
            dst[mi][ks] = *(const s16x8*)&lds[(b)*32768 +                    \
                (wm * 128 + (sub) + mi * 16 + rA) * 64 +                     \
                ((ks * 32 + kq) ^ xr)];                                      \
  } while (0)
#define RD_B(dst, b, sub)                                                    \
  do {                                                                       \
    _Pragma("unroll") for (int ni = 0; ni < 2; ++ni)                         \
        _Pragma("unroll") for (int ks = 0; ks < 2; ++ks)                     \
            dst[ni][ks] = *(const s16x8*)&lds[(b)*32768 + 16384 +            \
                (wn * 64 + (sub) + ni * 16 + rA) * 64 +                      \
                ((ks * 32 + kq) ^ xr)];                                      \
  } while (0)
#define MM(AF, BF, MO, NO)                                                   \
  do {                                                                       \
    _Pragma("unroll") for (int mi = 0; mi < 4; ++mi)                         \
        _Pragma("unroll") for (int ni = 0; ni < 2; ++ni)                     \
            _Pragma("unroll") for (int ks = 0; ks < 2; ++ks)                 \
                acc[(MO) + mi][(NO) + ni] =                                  \
                    __builtin_amdgcn_mfma_f32_16x16x32_bf16(                 \
                        AF[mi][ks], BF[ni][ks], acc[(MO) + mi][(NO) + ni],   \
                        0, 0, 0);                                            \
  } while (0)

  f32x4 acc[8][4] = {};
  const int NT = K >> 6;  // 16 (proj/scores) or 64 (PV): always even, >=4

  // prologue: K0->buf0, K1->buf1 fully; retire K0's 8 (K1's 8 in flight)
  STAGE_A(0, 0, 0);
  STAGE_A(1, 0, 0);
  STAGE_B(0, 0, 0);
  STAGE_B(1, 0, 0);
  STAGE_A(0, 1, 1);
  STAGE_A(1, 1, 1);
  STAGE_B(0, 1, 1);
  STAGE_B(1, 1, 1);
  WAITVM(8);
  BARRIER();

  s16x8 af0[4][2], af1[4][2], bf0[2][2], bf1[2][2];

  // m201 phase shape: {issue reads (+stage) -> barrier -> lgkm0 -> MFMA ->
  // barrier}. Read latency hides under the barrier wait.
#define KTILE(b, tt)                                                         \
  do {                                                                       \
    /* ph1 */                                                                \
    RD_A(af0, b, 0);                                                         \
    RD_B(bf0, b, 0);                                                         \
    BARRIER();                                                               \
    WAITLGKM0();                                                             \
    __builtin_amdgcn_s_setprio(1);                                           \
    MM(af0, bf0, 0, 0);                                                      \
    __builtin_amdgcn_s_setprio(0);                                           \
    BARRIER();                                                               \
    /* ph2: last A-reads */                                                  \
    RD_A(af1, b, 64);                                                        \
    BARRIER();                                                               \
    WAITLGKM0();                                                             \
    __builtin_amdgcn_s_setprio(1);                                           \
    MM(af1, bf0, 4, 0);                                                      \
    __builtin_amdgcn_s_setprio(0);                                           \
    BARRIER(); /* A-reads complete block-wide */                             \
    /* ph3: last B-reads; restage A(tt+2) into buf b */                      \
    RD_B(bf1, b, 32);                                                        \
    if ((tt) + 2 < NT) {                                                     \
      STAGE_A(0, (tt) + 2, b);                                               \
      STAGE_A(1, (tt) + 2, b);                                               \
    }                                                                        \
    BARRIER();                                                               \
    WAITLGKM0();                                                             \
    __builtin_amdgcn_s_setprio(1);                                           \
    MM(af0, bf1, 0, 2);                                                      \
    __builtin_amdgcn_s_setprio(0);                                           \
    BARRIER(); /* B-reads complete block-wide */                             \
    /* ph4: restage B(tt+2); counted vmcnt retires tile tt+1 */              \
    if ((tt) + 2 < NT) {                                                     \
      STAGE_B(0, (tt) + 2, b);                                               \
      STAGE_B(1, (tt) + 2, b);                                               \
      WAITVM(8);                                                             \
    } else if ((tt) + 1 < NT) {                                              \
      WAITVM(0);                                                             \
    }                                                                        \
    BARRIER();                                                               \
    __builtin_amdgcn_s_setprio(1);                                           \
    MM(af1, bf1, 4, 2);                                                      \
    __builtin_amdgcn_s_setprio(0);                                           \
    BARRIER();                                                               \
  } while (0)

  for (int t = 0; t < NT; t += 2) {
    KTILE(0, t);
    KTILE(1, t + 1);
  }
#undef KTILE

  // ---- coalesced epilogue via LDS: 4 chunks of 64 rows x 256 cols f32 ----
  // fl = [64][260] f32 (66560 B). rinv (MODE 3) lives just past fl.
  float* fl = (float*)lds;
  float* rinv = fl + 16640;  // 256 f32, bytes 66560..67583 < 131072
  const int l15 = lane & 15;
  const int r4 = (lane >> 4) * 4;
  f32x4 bcol4 = {0.f, 0.f, 0.f, 0.f};
  if (MODE == 0) bcol4 = *(const f32x4*)&bi[n0 + lane * 4];
  if (MODE == 3) {
    // precompute 1/rowsum for this block's 256 rows (coalesced 64B reads)
    if (tid < 256) {
      const float* pr = &part[((size_t)blockIdx.z * 4096 + m0 + tid) * 16];
      float s = 0.f;
#pragma unroll
      for (int j = 0; j < 4; ++j) {
        f32x4 t4 = *(const f32x4*)&pr[j * 4];
        s += (t4[0] + t4[1]) + (t4[2] + t4[3]);
      }
      rinv[tid] = 1.0f / s;
    }
  }
#pragma unroll
  for (int c = 0; c < 4; ++c) {
    __syncthreads();  // K-loop done / prior chunk's reads done (incl. rinv w)
    if (wm == (c >> 1)) {
      const int mibase = (c & 1) * 4;
#pragma unroll
      for (int mi = 0; mi < 4; ++mi) {
#pragma unroll
        for (int nj = 0; nj < 4; ++nj) {
          const int col = wn * 64 + nj * 16 + l15;
          const int rbase = mi * 16 + r4;
#pragma unroll
          for (int rr = 0; rr < 4; ++rr) {
            float v = acc[mibase + mi][nj][rr];
            if (MODE == 2) v = __expf(v * scale);  // exp fused here
            fl[(rbase + rr) * 260 + col] = v;
          }
        }
      }
    }
    __syncthreads();
#pragma unroll
    for (int p = 0; p < 8; ++p) {
      const int rl = p * 8 + wid;
      const int rowg = m0 + c * 64 + rl;
      f32x4 v = *(const f32x4*)&fl[rl * 260 + lane * 4];
      if (MODE == 0) {
#pragma unroll
        for (int j = 0; j < 4; ++j) v[j] += bcol4[j];
        u16x4 h;
#pragma unroll
        for (int j = 0; j < 4; ++j) h[j] = f2b(v[j]);
        ((u16x4*)((u16*)C + (size_t)rowg * ldc + n0))[lane] = h;
      } else if (MODE == 1) {
        const float br = bi[rowg];
        u16x4 h;
#pragma unroll
        for (int j = 0; j < 4; ++j) h[j] = f2b(v[j] + br);
        ((u16x4*)((u16*)C + (size_t)rowg * ldc + n0))[lane] = h;
      } else if (MODE == 2) {
        u16x4 h;  // values already exp'd in LDS
#pragma unroll
        for (int j = 0; j < 4; ++j) h[j] = f2b(v[j]);
        ((u16x4*)((u16*)C + (size_t)rowg * ldc + n0))[lane] = h;
      } else {
        const float iv = rinv[c * 64 + rl];  // wave-uniform LDS broadcast
#pragma unroll
        for (int j = 0; j < 4; ++j) v[j] *= iv;
        ((f32x4*)((float*)C + (size_t)rowg * ldc + n0))[lane] = v;
      }
    }
    if (MODE == 2) {
      // row partial sums from LDS: thread sums 32 floats of row tid>>3,
      // then 3 in-group shuffles (lanes differ in bits 0..2).
      const int row8 = tid >> 3;
      const int seg = tid & 7;
      const float* rp = &fl[row8 * 260 + seg * 32];
      f32x4 s4 = {0.f, 0.f, 0.f, 0.f};
#pragma unroll
      for (int j = 0; j < 8; ++j) {
        f32x4 t4 = *(const f32x4*)&rp[j * 4];
#pragma unroll
        for (int d = 0; d < 4; ++d) s4[d] += t4[d];
      }
      float s = (s4[0] + s4[1]) + (s4[2] + s4[3]);
      s += __shfl_xor(s, 1, 64);
      s += __shfl_xor(s, 2, 64);
      s += __shfl_xor(s, 4, 64);
      if (seg == 0)
        part[((size_t)blockIdx.z * 4096 + m0 + c * 64 + row8) * 16 +
             (n0 >> 8)] = s;
    }
  }
#undef STAGE_A
#undef STAGE_B
#undef RD_A
#undef RD_B
#undef MM
}

extern "C" void kernel_launch(void* const* d_in, const int* in_sizes, int n_in,
                              void* d_out, int out_size, void* d_ws,
                              size_t ws_size, hipStream_t stream) {
  const float* x = (const float*)d_in[0];
  const float* Wq = (const float*)d_in[1];
  const float* bq = (const float*)d_in[2];
  const float* Wk = (const float*)d_in[3];
  const float* bk = (const float*)d_in[4];
  const float* Wv = (const float*)d_in[5];
  const float* bv = (const float*)d_in[6];
  float* out = (float*)d_out;
  char* ws = (char*)d_ws;

  const size_t MB = 1ull << 20;
  u16* Qb = (u16*)(ws + 0 * MB);      // [4][4096][1024] bf16
  u16* Kb = (u16*)(ws + 32 * MB);     // [4][4096][1024] bf16 (adjacent to Qb)
  u16* VtAll = (u16*)(ws + 64 * MB);  // [1024][16384] bf16 (V^T all batches)
  u16* Xb = (u16*)(ws + 96 * MB);     // [16384][1024] bf16, dead after proj
  u16* Sc = (u16*)(ws + 96 * MB);     // [4][4096][4096] bf16 P~, reuses Xb
  u16* Wqb = (u16*)(ws + 224 * MB);
  u16* Wkb = Wqb + 1048576;           // adjacent: z-stride 1048576 elements
  u16* Wvb = Wqb + 2097152;
  float* part = (float*)(ws + 231 * MB);  // [4][4096][16] f32 partial sums

  hipFuncSetAttribute((const void*)k_gemm256<0>,
                      hipFuncAttributeMaxDynamicSharedMemorySize, 131072);
  hipFuncSetAttribute((const void*)k_gemm256<1>,
                      hipFuncAttributeMaxDynamicSharedMemorySize, 131072);
  hipFuncSetAttribute((const void*)k_gemm256<2>,
                      hipFuncAttributeMaxDynamicSharedMemorySize, 131072);
  hipFuncSetAttribute((const void*)k_gemm256<3>,
                      hipFuncAttributeMaxDynamicSharedMemorySize, 131072);

  // converts (x: 16,777,216 floats = 4,194,304 float4)
  k_cvt<<<16384, 256, 0, stream>>>(x, Xb, 4194304);
  k_cvt<<<1024, 256, 0, stream>>>(Wq, Wqb, 262144);
  k_cvt<<<1024, 256, 0, stream>>>(Wk, Wkb, 262144);
  k_cvt<<<1024, 256, 0, stream>>>(Wv, Wvb, 262144);

  dim3 blk(512);
  const size_t LDSB = 131072;
  // Q+K projections, one launch: z=0 -> Q (bq), z=1 -> K (bk)
  k_gemm256<0><<<dim3(4, 64, 2), blk, LDSB, stream>>>(
      Xb, Wqb, 1024, 1024, 1024, bq, bk, Qb, 1024, 1.f, 0, 1048576,
      (size_t)32 * MB, nullptr);
  // V^T projection: C[d][s] = Wv@X^T + bv[d]; M=1024, N=16384
  k_gemm256<1><<<dim3(64, 4, 1), blk, LDSB, stream>>>(
      Wvb, Xb, 1024, 1024, 1024, bv, nullptr, VtAll, 16384, 1.f, 0, 0, 0,
      nullptr);
  // scores (all batches): P~ = exp(QK^T/32) bf16 + row partial sums
  k_gemm256<2><<<dim3(16, 16, 4), blk, LDSB, stream>>>(
      Qb, Kb, 1024, 1024, 1024, nullptr, nullptr, Sc, 4096, 0.03125f, 4194304,
      4194304, (size_t)4096 * 4096 * 2, part);
  // PV (all batches): out = (P~ V) / rowsum; M=4096, N=1024, K=4096
  k_gemm256<3><<<dim3(4, 16, 4), blk, LDSB, stream>>>(
      Sc, VtAll, 4096, 16384, 4096, nullptr, nullptr, out, 1024, 1.f, 16777216,
      4096, (size_t)4096 * 1024 * 4, part);
}

// Round 17
// 407.418 us; speedup vs baseline: 5.6081x; 1.0183x over previous
//
#include <hip/hip_runtime.h>
#include <hip/hip_bf16.h>
#include <stdint.h>

// SelfAttention B=4 S=4096 D=1024, fp32 in/out. Single-bf16 pipeline:
//   cvt -> {Q,K} proj (one z=2 launch), Vt = Wv@X^T (transposed direct)
//   -> scores kernel: P~ = exp(QK^T/32) bf16 + per-row partial sums (z=4)
//   -> PV kernel: out = (P~ V) / rowsum (z=4). No softmax kernel.
// R17 vs R13: K-loop re-phased to 2 phases/K-tile (untried midpoint between
// r13's 4-phase/4-barrier (413us) and r14's 1-phase bulk (425us)):
//   ph1: read af0(8)+bf_all(8); stage A(t+1)->buf b^1; lgkm0; 32 MFMA
//        (af0 x bf_all); BARRIER#1 (B_b reads complete block-wide)
//   ph2: read af1(8); stage B(t+2)->buf b; lgkm0; 32 MFMA (af1 x bf_all);
//        vmcnt(4) (retires A(t+1)+B(t+1), staged 2-3 phases before use);
//        BARRIER#2
// Rationale: per K-tile, 192 ds_read_b128 (~750cyc at 256B/clk LDS) vs 512
// MFMA (~620 CU-cyc) -> ~80% util possible if read/MFMA pipes overlap
// across waves; 4 lockstep phases re-correlate the 2 waves/SIMD 4x per
// tile, killing the overlap. Fewer/bigger phases + even 4-gload staging.
// WAR ledger: B_b last read ph1 -> restage ph2 after #1; A_{b^1} last read
// prior-iter ph2 -> restage ph1 after prior #2; next-tile reads gated by
// vmcnt(4)+#2. Prologue: tile0 full + B(1); vmcnt(4) leaves B(1) in flight.
// R15 lesson: never force min-waves via __launch_bounds__ (acc=128 f32/lane
// -> scratch spill). GEMM: 256x256, BK=64, 8 waves (2Mx4N), 16x16x32 MFMA,
// T2 st-XOR swizzle, T1 bijective XCD swizzle, coalesced LDS epilogue with
// fused exp/rowsum (MODE 2) and rowsum^-1 (MODE 3).

typedef __attribute__((ext_vector_type(4))) float f32x4;
typedef __attribute__((ext_vector_type(8))) short s16x8;
typedef __attribute__((ext_vector_type(4))) unsigned short u16x4;
typedef unsigned int u32;
typedef unsigned short u16;

__device__ __forceinline__ u16 f2b(float f) {   // fp32 -> bf16 RNE
  u32 u = __float_as_uint(f);
  u = (u + 0x7FFFu + ((u >> 16) & 1u)) >> 16;
  return (u16)u;
}
__device__ __forceinline__ float b2f(u16 h) {
  return __uint_as_float(((u32)h) << 16);
}

__device__ __forceinline__ void gload_lds16(const void* g, void* l) {
  __builtin_amdgcn_global_load_lds(
      (const __attribute__((address_space(1))) void*)(const void*)g,
      (__attribute__((address_space(3))) void*)(void*)l, 16, 0, 0);
}

#define BARRIER() asm volatile("s_barrier" ::: "memory")
#define WAITLGKM0() asm volatile("s_waitcnt lgkmcnt(0)" ::: "memory")
#define WAITVM(N) asm volatile("s_waitcnt vmcnt(" #N ")" ::: "memory")

// ---------------- fp32 -> bf16 convert ----------------
__global__ __launch_bounds__(256) void k_cvt(const float* __restrict__ in,
                                             u16* __restrict__ out, int n4) {
  int i = blockIdx.x * 256 + threadIdx.x;
  if (i >= n4) return;
  f32x4 f = ((const f32x4*)in)[i];
  u16x4 h;
#pragma unroll
  for (int j = 0; j < 4; ++j) h[j] = f2b(f[j]);
  ((u16x4*)out)[i] = h;
}

// ------------- 256^2 2-phase NT GEMM, 16x16x32 bf16 MFMA -------------
// C[M,N] = sum_k A[m,k]*B[n,k].
// MODE 0: bias[col] + bf16 store (Q/K proj; z=1 uses biasB)
// MODE 1: bias[row] + bf16 store (V^T proj)
// MODE 2: bf16 store of exp(v*scale); per-row partial sums -> part
// MODE 3: fp32 store of v / rowsum (rowsum = sum of 16 partials) (PV out)
template <int MODE>
__global__ __launch_bounds__(512)
void k_gemm256(const u16* __restrict__ A, const u16* __restrict__ B, int lda,
               int ldb, int K, const float* __restrict__ bias,
               const float* __restrict__ biasB, void* __restrict__ Cv, int ldc,
               float scale, size_t az, size_t bz, size_t czb,
               float* __restrict__ part) {
  extern __shared__ __align__(16) u16 lds[];  // 131072 B

  A += (size_t)blockIdx.z * az;
  B += (size_t)blockIdx.z * bz;
  char* C = (char*)Cv + (size_t)blockIdx.z * czb;
  const float* bi = (MODE == 0 && blockIdx.z != 0) ? biasB : bias;

  // bijective XCD-aware swizzle
  const int gx = gridDim.x;
  const int nwg = gx * gridDim.y;
  const int bid = blockIdx.y * gx + blockIdx.x;
  const int q = nwg >> 3, r = nwg & 7;
  const int xcd = bid & 7, idx = bid >> 3;
  const int tile = (xcd < r ? xcd * (q + 1) : r * (q + 1) + (xcd - r) * q) + idx;
  const int m0 = (tile / gx) * 256;
  const int n0 = (tile % gx) * 256;

  const int tid = threadIdx.x;
  const int lane = tid & 63;
  const int wid = tid >> 6;
  const int wm = wid >> 2;  // 0..1 (M half)
  const int wn = wid & 3;   // 0..3 (N quarter)

  // staging: one STAGE = one 128x64 half-tile = 2 gload_lds per thread
  const int srow = lane >> 3;                       // 0..7
  const int gcol = (((lane & 7) ^ srow) << 3);      // inverse-swizzled col
  // ds_read constants (16x16 layout, conflict-free measured r5)
  const int rA = lane & 15;
  const int kq = (lane >> 4) << 3;                  // 0,8,16,24
  const int xr = (lane & 7) << 3;                   // read-side swizzle

#define STAGE_A(h, kt, b)                                                    \
  do {                                                                       \
    _Pragma("unroll") for (int j = 0; j < 2; ++j)                            \
        gload_lds16(A + (size_t)(m0 + (h)*128 + j * 64 + wid * 8 + srow) *   \
                            lda + (kt)*64 + gcol,                            \
                    &lds[(b)*32768 + (h)*8192 + j * 4096 + wid * 512]);      \
  } while (0)
#define STAGE_B(h, kt, b)                                                    \
  do {                                                                       \
    _Pragma("unroll") for (int j = 0; j < 2; ++j)                            \
        gload_lds16(B + (size_t)(n0 + (h)*128 + j * 64 + wid * 8 + srow) *   \
                            ldb + (kt)*64 + gcol,                            \
                    &lds[(b)*32768 + 16384 + (h)*8192 + j * 4096 +           \
                         wid * 512]);                                        \
  } while (0)
#define RD_A(dst, b, sub)                                                    \
  do {                                                                       \
    _Pragma("unroll") for (int mi = 0; mi < 4; ++mi)                         \
        _Pragma("unroll") for (int ks = 0; ks < 2; ++ks)                     \
            dst[mi][ks] = *(const s16x8*)&lds[(b)*32768 +                    \
                (wm * 128 + (sub) + mi * 16 + rA) * 64 +                     \
                ((ks * 32 + kq) ^ xr)];                                      \
  } while (0)
#define RD_BALL(dst, b)                                                      \
  do {                                                                       \
    _Pragma("unroll") for (int nj = 0; nj < 4; ++nj)                         \
        _Pragma("unroll") for (int ks = 0; ks < 2; ++ks)                     \
            dst[nj][ks] = *(const s16x8*)&lds[(b)*32768 + 16384 +            \
                (wn * 64 + nj * 16 + rA) * 64 +                              \
                ((ks * 32 + kq) ^ xr)];                                      \
  } while (0)
// 32 MFMA: af (4 mi) x bf (4 nj) x 2 ks (r13 ordering, ks innermost)
#define MM2(AF, BF, MO)                                                      \
  do {                                                                       \
    _Pragma("unroll") for (int mi = 0; mi < 4; ++mi)                         \
        _Pragma("unroll") for (int nj = 0; nj < 4; ++nj)                     \
            _Pragma("unroll") for (int ks = 0; ks < 2; ++ks)                 \
                acc[(MO) + mi][nj] =                                         \
                    __builtin_amdgcn_mfma_f32_16x16x32_bf16(                 \
                        AF[mi][ks], BF[nj][ks], acc[(MO) + mi][nj],          \
                        0, 0, 0);                                            \
  } while (0)

  f32x4 acc[8][4] = {};
  const int NT = K >> 6;  // 16 (proj/scores) or 64 (PV)

  // prologue: tile0 -> buf0 (8 loads); B(1) -> buf1 (4 loads).
  // vmcnt(4) retires tile0, leaves B(1) in flight (invariant at loop top:
  // outstanding = [B(t+1):4]).
  STAGE_A(0, 0, 0);
  STAGE_A(1, 0, 0);
  STAGE_B(0, 0, 0);
  STAGE_B(1, 0, 0);
  if (NT > 1) {
    STAGE_B(0, 1, 1);
    STAGE_B(1, 1, 1);
    WAITVM(4);
  } else {
    WAITVM(0);
  }
  BARRIER();

  s16x8 af0[4][2], af1[4][2], bf[4][2];
  for (int t = 0; t < NT; ++t) {
    const int b = t & 1;
    // ph1: read af0 + all B frags; stage A(t+1) into buf b^1
    // (A_{b^1} last read at (t-1).ph2, certified by (t-1) BARRIER#2)
    RD_A(af0, b, 0);
    RD_BALL(bf, b);
    if (t + 1 < NT) {
      STAGE_A(0, t + 1, b ^ 1);
      STAGE_A(1, t + 1, b ^ 1);
    }
    WAITLGKM0();
    __builtin_amdgcn_s_setprio(1);
    MM2(af0, bf, 0);
    __builtin_amdgcn_s_setprio(0);
    BARRIER();  // #1: all waves' B_b reads (bf_all, ph1-only) complete
    // ph2: read af1; stage B(t+2) into buf b (B_b freed by #1)
    RD_A(af1, b, 64);
    if (t + 2 < NT) {
      STAGE_B(0, t + 2, b);
      STAGE_B(1, t + 2, b);
    }
    WAITLGKM0();
    __builtin_amdgcn_s_setprio(1);
    MM2(af1, bf, 4);
    __builtin_amdgcn_s_setprio(0);
    // retire tile t+1's 8 loads (A staged this ph1, B staged (t-1).ph2);
    // keep B(t+2)'s 4 in flight. Tail: drain fully.
    if (t + 2 < NT) {
      WAITVM(4);
    } else {
      WAITVM(0);
    }
    BARRIER();  // #2: next iter may read buf b^1 = tile t+1
  }

  // ---- coalesced epilogue via LDS: 4 chunks of 64 rows x 256 cols f32 ----
  // fl = [64][260] f32 (66560 B). rinv (MODE 3) lives just past fl.
  float* fl = (float*)lds;
  float* rinv = fl + 16640;  // 256 f32, bytes 66560..67583 < 131072
  const int l15 = lane & 15;
  const int r4 = (lane >> 4) * 4;
  f32x4 bcol4 = {0.f, 0.f, 0.f, 0.f};
  if (MODE == 0) bcol4 = *(const f32x4*)&bi[n0 + lane * 4];
  if (MODE == 3) {
    // precompute 1/rowsum for this block's 256 rows (coalesced 64B reads)
    if (tid < 256) {
      const float* pr = &part[((size_t)blockIdx.z * 4096 + m0 + tid) * 16];
      float s = 0.f;
#pragma unroll
      for (int j = 0; j < 4; ++j) {
        f32x4 t4 = *(const f32x4*)&pr[j * 4];
        s += (t4[0] + t4[1]) + (t4[2] + t4[3]);
      }
      rinv[tid] = 1.0f / s;
    }
  }
#pragma unroll
  for (int c = 0; c < 4; ++c) {
    __syncthreads();  // K-loop done / prior chunk's reads done (incl. rinv w)
    if (wm == (c >> 1)) {
      const int mibase = (c & 1) * 4;
#pragma unroll
      for (int mi = 0; mi < 4; ++mi) {
#pragma unroll
        for (int nj = 0; nj < 4; ++nj) {
          const int col = wn * 64 + nj * 16 + l15;
          const int rbase = mi * 16 + r4;
#pragma unroll
          for (int rr = 0; rr < 4; ++rr) {
            float v = acc[mibase + mi][nj][rr];
            if (MODE == 2) v = __expf(v * scale);  // exp fused here
            fl[(rbase + rr) * 260 + col] = v;
          }
        }
      }
    }
    __syncthreads();
#pragma unroll
    for (int p = 0; p < 8; ++p) {
      const int rl = p * 8 + wid;
      const int rowg = m0 + c * 64 + rl;
      f32x4 v = *(const f32x4*)&fl[rl * 260 + lane * 4];
      if (MODE == 0) {
#pragma unroll
        for (int j = 0; j < 4; ++j) v[j] += bcol4[j];
        u16x4 h;
#pragma unroll
        for (int j = 0; j < 4; ++j) h[j] = f2b(v[j]);
        ((u16x4*)((u16*)C + (size_t)rowg * ldc + n0))[lane] = h;
      } else if (MODE == 1) {
        const float br = bi[rowg];
        u16x4 h;
#pragma unroll
        for (int j = 0; j < 4; ++j) h[j] = f2b(v[j] + br);
        ((u16x4*)((u16*)C + (size_t)rowg * ldc + n0))[lane] = h;
      } else if (MODE == 2) {
        u16x4 h;  // values already exp'd in LDS
#pragma unroll
        for (int j = 0; j < 4; ++j) h[j] = f2b(v[j]);
        ((u16x4*)((u16*)C + (size_t)rowg * ldc + n0))[lane] = h;
      } else {
        const float iv = rinv[c * 64 + rl];  // wave-uniform LDS broadcast
#pragma unroll
        for (int j = 0; j < 4; ++j) v[j] *= iv;
        ((f32x4*)((float*)C + (size_t)rowg * ldc + n0))[lane] = v;
      }
    }
    if (MODE == 2) {
      // row partial sums from LDS: thread sums 32 floats of row tid>>3,
      // then 3 in-group shuffles (lanes differ in bits 0..2).
      const int row8 = tid >> 3;
      const int seg = tid & 7;
      const float* rp = &fl[row8 * 260 + seg * 32];
      f32x4 s4 = {0.f, 0.f, 0.f, 0.f};
#pragma unroll
      for (int j = 0; j < 8; ++j) {
        f32x4 t4 = *(const f32x4*)&rp[j * 4];
#pragma unroll
        for (int d = 0; d < 4; ++d) s4[d] += t4[d];
      }
      float s = (s4[0] + s4[1]) + (s4[2] + s4[3]);
      s += __shfl_xor(s, 1, 64);
      s += __shfl_xor(s, 2, 64);
      s += __shfl_xor(s, 4, 64);
      if (seg == 0)
        part[((size_t)blockIdx.z * 4096 + m0 + c * 64 + row8) * 16 +
             (n0 >> 8)] = s;
    }
  }
#undef STAGE_A
#undef STAGE_B
#undef RD_A
#undef RD_BALL
#undef MM2
}

extern "C" void kernel_launch(void* const* d_in, const int* in_sizes, int n_in,
                              void* d_out, int out_size, void* d_ws,
                              size_t ws_size, hipStream_t stream) {
  const float* x = (const float*)d_in[0];
  const float* Wq = (const float*)d_in[1];
  const float* bq = (const float*)d_in[2];
  const float* Wk = (const float*)d_in[3];
  const float* bk = (const float*)d_in[4];
  const float* Wv = (const float*)d_in[5];
  const float* bv = (const float*)d_in[6];
  float* out = (float*)d_out;
  char* ws = (char*)d_ws;

  const size_t MB = 1ull << 20;
  u16* Qb = (u16*)(ws + 0 * MB);      // [4][4096][1024] bf16
  u16* Kb = (u16*)(ws + 32 * MB);     // [4][4096][1024] bf16 (adjacent to Qb)
  u16* VtAll = (u16*)(ws + 64 * MB);  // [1024][16384] bf16 (V^T all batches)
  u16* Xb = (u16*)(ws + 96 * MB);     // [16384][1024] bf16, dead after proj
  u16* Sc = (u16*)(ws + 96 * MB);     // [4][4096][4096] bf16 P~, reuses Xb
  u16* Wqb = (u16*)(ws + 224 * MB);
  u16* Wkb = Wqb + 1048576;           // adjacent: z-stride 1048576 elements
  u16* Wvb = Wqb + 2097152;
  float* part = (float*)(ws + 231 * MB);  // [4][4096][16] f32 partial sums

  hipFuncSetAttribute((const void*)k_gemm256<0>,
                      hipFuncAttributeMaxDynamicSharedMemorySize, 131072);
  hipFuncSetAttribute((const void*)k_gemm256<1>,
                      hipFuncAttributeMaxDynamicSharedMemorySize, 131072);
  hipFuncSetAttribute((const void*)k_gemm256<2>,
                      hipFuncAttributeMaxDynamicSharedMemorySize, 131072);
  hipFuncSetAttribute((const void*)k_gemm256<3>,
                      hipFuncAttributeMaxDynamicSharedMemorySize, 131072);

  // converts (x: 16,777,216 floats = 4,194,304 float4)
  k_cvt<<<16384, 256, 0, stream>>>(x, Xb, 4194304);
  k_cvt<<<1024, 256, 0, stream>>>(Wq, Wqb, 262144);
  k_cvt<<<1024, 256, 0, stream>>>(Wk, Wkb, 262144);
  k_cvt<<<1024, 256, 0, stream>>>(Wv, Wvb, 262144);

  dim3 blk(512);
  const size_t LDSB = 131072;
  // Q+K projections, one launch: z=0 -> Q (bq), z=1 -> K (bk)
  k_gemm256<0><<<dim3(4, 64, 2), blk, LDSB, stream>>>(
      Xb, Wqb, 1024, 1024, 1024, bq, bk, Qb, 1024, 1.f, 0, 1048576,
      (size_t)32 * MB, nullptr);
  // V^T projection: C[d][s] = Wv@X^T + bv[d]; M=1024, N=16384
  k_gemm256<1><<<dim3(64, 4, 1), blk, LDSB, stream>>>(
      Wvb, Xb, 1024, 1024, 1024, bv, nullptr, VtAll, 16384, 1.f, 0, 0, 0,
      nullptr);
  // scores (all batches): P~ = exp(QK^T/32) bf16 + row partial sums
  k_gemm256<2><<<dim3(16, 16, 4), blk, LDSB, stream>>>(
      Qb, Kb, 1024, 1024, 1024, nullptr, nullptr, Sc, 4096, 0.03125f, 4194304,
      4194304, (size_t)4096 * 4096 * 2, part);
  // PV (all batches): out = (P~ V) / rowsum; M=4096, N=1024, K=4096
  k_gemm256<3><<<dim3(4, 16, 4), blk, LDSB, stream>>>(
      Sc, VtAll, 4096, 16384, 4096, nullptr, nullptr, out, 1024, 1.f, 16777216,
      4096, (size_t)4096 * 1024 * 4, part);
}